// Round 9
// baseline (584.212 us; speedup 1.0000x reference)
//
#include <hip/hip_runtime.h>

// GCN 2-layer, N=200000, E=3200000.
// R8 evidence: no single kernel dominates (k_bin 43us, six others sum ~156us).
// The pass structure is the cost: 7 launches, epack written+re-read 3x, each
// kernel pays its own latency ramp. R9: ONE persistent kernel (391 blocks x
// 512 threads, all co-resident), manual device-scope grid barriers; the
// sorted adjacency lives in LDS across phases (never written to global).
// Phases: hist -> scan -> bin -> build(sort in LDS) -> agg1 -> agg2.

#define BS    512
#define CH    8192                 // edges per chunk-block
#define NBW   512                  // nodes per bucket
#define SH    9                    // log2(NBW)
#define NBP   392                  // bucket array stride (nblk = 391)
#define CAP   9216                 // LDS stage capacity (mean 8184, +11 sigma)
#define RSTG  ((CAP + BS - 1) / BS)  // 18 regs/thread for the sort staging

__device__ __forceinline__ void grid_barrier(unsigned* cnt, unsigned target) {
    __syncthreads();
    if (threadIdx.x == 0) {
        __threadfence();   // release: flush this XCD's writes to coherence point
        __hip_atomic_fetch_add(cnt, 1u, __ATOMIC_ACQ_REL, __HIP_MEMORY_SCOPE_AGENT);
        int guard = 0;     // bailout: wrong-but-terminating beats a hang
        while (__hip_atomic_load(cnt, __ATOMIC_ACQUIRE, __HIP_MEMORY_SCOPE_AGENT) < target
               && guard < 2000000) { __builtin_amdgcn_s_sleep(2); ++guard; }
        __threadfence();   // acquire: invalidate stale cached lines
    }
    __syncthreads();
}

__global__ void __launch_bounds__(BS, 4)
k_fused(const int* __restrict__ srca, const int* __restrict__ dsta,
        const float* __restrict__ x,
        const float* __restrict__ W1, const float* __restrict__ b1,
        const float* __restrict__ W2, const float* __restrict__ b2,
        unsigned* __restrict__ blockHist, unsigned* __restrict__ blockOfs,
        unsigned* __restrict__ total, unsigned* __restrict__ epack,
        float* __restrict__ x_scaled, float* __restrict__ z_scaled,
        float* __restrict__ out, unsigned* __restrict__ bar,
        int E, int N, int nblk) {
    __shared__ unsigned stage[CAP];   // packed edges, then sorted src lists
    __shared__ unsigned hh[NBP];      // hist counts / bin cursors
    __shared__ unsigned bb[NBP];      // aligned bucket bases
    __shared__ unsigned cnt[BS];      // per-node degree (persists to agg)
    __shared__ unsigned sc[BS];       // inclusive scan  (persists to agg)
    __shared__ unsigned cur[BS];      // sort cursors

    const int b = blockIdx.x, t = threadIdx.x;
    const unsigned G = (unsigned)nblk;

    // ---- P1: per-chunk bucket histogram ----
    for (int i = t; i < NBP; i += BS) hh[i] = 0;
    __syncthreads();
    {
        int lo = b * CH, hi = min(E, lo + CH);
        for (int i = lo + 4 * t; i + 3 < hi; i += 4 * BS) {
            int4 d4 = *(const int4*)(dsta + i);
            atomicAdd(&hh[((unsigned)d4.x) >> SH], 1u);
            atomicAdd(&hh[((unsigned)d4.y) >> SH], 1u);
            atomicAdd(&hh[((unsigned)d4.z) >> SH], 1u);
            atomicAdd(&hh[((unsigned)d4.w) >> SH], 1u);
        }
    }
    __syncthreads();
    for (int i = t; i < NBP; i += BS) blockHist[(size_t)b * NBP + i] = hh[i];
    grid_barrier(bar, 1 * G);

    // ---- P2: per-bucket (bucket = b) exclusive scan over chunk-blocks ----
    {
        unsigned v = (t < nblk) ? blockHist[(size_t)t * NBP + b] : 0;
        sc[t] = v;
        __syncthreads();
        for (int off = 1; off < BS; off <<= 1) {
            unsigned u = (t >= off) ? sc[t - off] : 0;
            __syncthreads();
            sc[t] += u;
            __syncthreads();
        }
        if (t < nblk) blockOfs[(size_t)t * NBP + b] = sc[t] - v;
        if (t == nblk - 1) total[b] = sc[t];
    }
    grid_barrier(bar, 2 * G);

    // ---- P3: every block locally scans bucket totals -> aligned bases bb ----
    {
        unsigned tot = (t < nblk) ? total[t] : 0;
        unsigned sz = (tot + 3u) & ~3u;            // 16B-align each bucket base
        sc[t] = sz;
        __syncthreads();
        for (int off = 1; off < BS; off <<= 1) {
            unsigned u = (t >= off) ? sc[t - off] : 0;
            __syncthreads();
            sc[t] += u;
            __syncthreads();
        }
        if (t < NBP) bb[t] = sc[t] - sz;
        __syncthreads();
    }

    // ---- P4: bin packed edges into bucket segments ----
    {
        for (int i = t; i < NBP; i += BS)
            hh[i] = bb[i] + blockOfs[(size_t)b * NBP + i];
        __syncthreads();
        int lo = b * CH, hi = min(E, lo + CH);
        for (int i = lo + 4 * t; i + 3 < hi; i += 4 * BS) {
            int4 d4 = *(const int4*)(dsta + i);
            int4 s4 = *(const int4*)(srca + i);
            unsigned p0 = atomicAdd(&hh[((unsigned)d4.x) >> SH], 1u);
            unsigned p1 = atomicAdd(&hh[((unsigned)d4.y) >> SH], 1u);
            unsigned p2 = atomicAdd(&hh[((unsigned)d4.z) >> SH], 1u);
            unsigned p3 = atomicAdd(&hh[((unsigned)d4.w) >> SH], 1u);
            epack[p0] = ((unsigned)s4.x << SH) | (((unsigned)d4.x) & (NBW - 1u));
            epack[p1] = ((unsigned)s4.y << SH) | (((unsigned)d4.y) & (NBW - 1u));
            epack[p2] = ((unsigned)s4.z << SH) | (((unsigned)d4.z) & (NBW - 1u));
            epack[p3] = ((unsigned)s4.w << SH) | (((unsigned)d4.w) & (NBW - 1u));
        }
    }
    grid_barrier(bar, 3 * G);

    // ---- P5: build — stage bucket b, count, scan, sort in LDS ----
    float di = 0.0f;
    float4 xs = make_float4(0.f, 0.f, 0.f, 0.f);
    const int node = b * NBW + t;
    {
        unsigned klo = bb[b];
        int len = min((int)total[b], CAP);
        for (int i = 4 * t; i + 3 < len; i += 4 * BS)
            *(int4*)&stage[i] = *(const int4*)(epack + klo + i);
        if (t < (len & 3)) stage[(len & ~3) + t] = epack[klo + (len & ~3) + t];
        cnt[t] = 0;
        __syncthreads();
        for (int i = t; i < len; i += BS) atomicAdd(&cnt[stage[i] & (NBW - 1u)], 1u);
        __syncthreads();
        unsigned c = cnt[t];
        sc[t] = c;
        __syncthreads();
        for (int off = 1; off < BS; off <<= 1) {
            unsigned u = (t >= off) ? sc[t - off] : 0;
            __syncthreads();
            sc[t] += u;
            __syncthreads();
        }
        cur[t] = sc[t] - c;
        if (node < N) {
            di = rsqrtf((float)(c + 1));           // +1: self loop
            float4 xv = ((const float4*)x)[node];
            xs = make_float4(xv.x * di, xv.y * di, xv.z * di, xv.w * di);
            ((float4*)x_scaled)[node] = xs;
        }
        __syncthreads();
        unsigned r[RSTG];                           // lift to regs, then sort
        int nr = 0;
        for (int i = t; i < len; i += BS) r[nr++] = stage[i];
        __syncthreads();
        for (int j = 0; j < nr; ++j) {
            unsigned p = r[j];
            unsigned pos = atomicAdd(&cur[p & (NBW - 1u)], 1u);
            stage[pos] = p >> SH;                   // stage = sorted src lists
        }
    }
    grid_barrier(bar, 4 * G);                       // all x_scaled visible

    // ---- P6: layer-1 pull aggregation + fused node math ----
    float zs = 0.0f;
    if (node < N) {
        unsigned c = cnt[t];
        unsigned lo = sc[t] - c, hi = sc[t];
        const float4* xs4 = (const float4*)x_scaled;
        float4 a0 = xs;                             // self loop
        float4 a1 = make_float4(0.f, 0.f, 0.f, 0.f);
        float4 a2 = make_float4(0.f, 0.f, 0.f, 0.f);
        float4 a3 = make_float4(0.f, 0.f, 0.f, 0.f);
        unsigned i = lo;
        for (; i + 3 < hi; i += 4) {                // 4 gathers in flight
            float4 v0 = xs4[stage[i]],     v1 = xs4[stage[i + 1]];
            float4 v2 = xs4[stage[i + 2]], v3 = xs4[stage[i + 3]];
            a0.x += v0.x; a0.y += v0.y; a0.z += v0.z; a0.w += v0.w;
            a1.x += v1.x; a1.y += v1.y; a1.z += v1.z; a1.w += v1.w;
            a2.x += v2.x; a2.y += v2.y; a2.z += v2.z; a2.w += v2.w;
            a3.x += v3.x; a3.y += v3.y; a3.z += v3.z; a3.w += v3.w;
        }
        for (; i < hi; ++i) {
            float4 v = xs4[stage[i]];
            a0.x += v.x; a0.y += v.y; a0.z += v.z; a0.w += v.w;
        }
        float p0 = di * (a0.x + a1.x + a2.x + a3.x);
        float p1 = di * (a0.y + a1.y + a2.y + a3.y);
        float p2 = di * (a0.z + a1.z + a2.z + a3.z);
        float p3 = di * (a0.w + a1.w + a2.w + a3.w);
        float z = 0.0f;
        #pragma unroll
        for (int cc = 0; cc < 16; ++cc) {
            float h1 = p0 * W1[0 * 16 + cc] + p1 * W1[1 * 16 + cc]
                     + p2 * W1[2 * 16 + cc] + p3 * W1[3 * 16 + cc] + b1[cc];
            h1 = fmaxf(h1, 0.0f);
            z += h1 * W2[cc];
        }
        zs = z * di;
        z_scaled[node] = zs;
    }
    grid_barrier(bar, 5 * G);                       // all z_scaled visible

    // ---- P7: layer-2 pull aggregation ----
    if (node < N) {
        unsigned c = cnt[t];
        unsigned lo = sc[t] - c, hi = sc[t];
        float a0 = zs, a1 = 0.f, a2 = 0.f, a3 = 0.f; // self loop in a0
        unsigned i = lo;
        for (; i + 3 < hi; i += 4) {
            a0 += z_scaled[stage[i]];
            a1 += z_scaled[stage[i + 1]];
            a2 += z_scaled[stage[i + 2]];
            a3 += z_scaled[stage[i + 3]];
        }
        for (; i < hi; ++i) a0 += z_scaled[stage[i]];
        out[node] = di * (a0 + a1 + a2 + a3) + b2[0];
    }
}

extern "C" void kernel_launch(void* const* d_in, const int* in_sizes, int n_in,
                              void* d_out, int out_size, void* d_ws, size_t ws_size,
                              hipStream_t stream) {
    const float* x  = (const float*)d_in[0];
    const int*   ei = (const int*)d_in[1];   // [2, E] as int32
    const float* W1 = (const float*)d_in[2];
    const float* b1 = (const float*)d_in[3];
    const float* W2 = (const float*)d_in[4];
    const float* b2 = (const float*)d_in[5];

    const int N = in_sizes[0] / 4;
    const int E = in_sizes[1] / 2;
    const int* src = ei;
    const int* dst = ei + E;
    const int NA = (E + CH - 1) / CH;        // 391
    const int nb = (N + NBW - 1) / NBW;      // 391
    const int nblk = (NA > nb) ? NA : nb;    // 391 (<= 512 for the scans)

    // Workspace (~18 MB): bar | blockHist | blockOfs | total | epack | x_scaled | z_scaled
    char* ws = (char*)d_ws;
    unsigned* bar       = (unsigned*)ws;  ws += 256;
    unsigned* blockHist = (unsigned*)ws;  ws += (size_t)nblk * NBP * 4;
    unsigned* blockOfs  = (unsigned*)ws;  ws += (size_t)nblk * NBP * 4;
    unsigned* total     = (unsigned*)ws;  ws += (size_t)NBP * 4;
    unsigned* epack     = (unsigned*)ws;  ws += ((size_t)E + 4 * NBP) * 4;
    float*    x_scaled  = (float*)ws;     ws += (size_t)N * 4 * 4;
    float*    z_scaled  = (float*)ws;     ws += (size_t)N * 4;
    float* out = (float*)d_out;

    hipMemsetAsync(bar, 0, 256, stream);     // barrier counter must start at 0
    k_fused<<<nblk, BS, 0, stream>>>(src, dst, x, W1, b1, W2, b2,
                                     blockHist, blockOfs, total, epack,
                                     x_scaled, z_scaled, out, bar, E, N, nblk);
}

// Round 10
// 170.776 us; speedup vs baseline: 3.4209x; 3.4209x over previous
//
#include <hip/hip_runtime.h>

// GCN 2-layer, N=200000, E=3200000.
// R9 post-mortem: software grid barrier = 80us/each (XCD L2 flush) -> revert
// to split kernels. R10 on R8 base: CH=16384 (longer bin runs, less write
// amp), k_build sorts in LDS + coalesced int4 writeback (R8 scatter-wrote 4B
// global), fixed-stride bucket segments (no scan_base, no base[]), dinv
// recomputed from rowcnt (no dinv array). 6 launches.

#define BSE   1024   // block size, hist/bin
#define CH    16384  // edges per hist/bin block
#define NBW   512    // nodes per bucket
#define SH    9      // log2(NBW)
#define NBP   392    // bucket array stride (runtime nb = 391)
#define FCAP  9216   // fixed bucket segment capacity (mean 8184, +11 sigma)
#define BSB   512    // build block size
#define RSTG  ((FCAP + BSB - 1) / BSB)   // 18 staging regs

// A1: per-chunk bucket histogram (LDS).
__global__ void k_hist(const int* __restrict__ dst, int E,
                       unsigned* __restrict__ blockHist) {
    __shared__ unsigned h[NBP];
    for (int i = threadIdx.x; i < NBP; i += BSE) h[i] = 0;
    __syncthreads();
    int b = blockIdx.x, t = threadIdx.x;
    int lo = b * CH, hi = min(E, lo + CH);
    int i = lo + 4 * t;
    for (; i + 3 < hi; i += 4 * BSE) {
        int4 d4 = *(const int4*)(dst + i);
        atomicAdd(&h[((unsigned)d4.x) >> SH], 1u);
        atomicAdd(&h[((unsigned)d4.y) >> SH], 1u);
        atomicAdd(&h[((unsigned)d4.z) >> SH], 1u);
        atomicAdd(&h[((unsigned)d4.w) >> SH], 1u);
    }
    for (i = lo + (((hi - lo) & ~3)) + t; i < hi; i += BSE)
        atomicAdd(&h[((unsigned)dst[i]) >> SH], 1u);
    __syncthreads();
    for (int j = threadIdx.x; j < NBP; j += BSE)
        blockHist[(size_t)b * NBP + j] = h[j];
}

// A2: per bucket k, exclusive scan over the NA chunk-blocks -> blockOfs, total.
__global__ void k_scan_col(const unsigned* __restrict__ blockHist,
                           unsigned* __restrict__ blockOfs,
                           unsigned* __restrict__ total, int NA) {
    int k = blockIdx.x, t = threadIdx.x;           // 256 threads, NA <= 256
    unsigned v = (t < NA) ? blockHist[(size_t)t * NBP + k] : 0;
    __shared__ unsigned sums[256];
    sums[t] = v;
    __syncthreads();
    for (int off = 1; off < 256; off <<= 1) {
        unsigned u = (t >= off) ? sums[t - off] : 0;
        __syncthreads();
        sums[t] += u;
        __syncthreads();
    }
    if (t < NA) blockOfs[(size_t)t * NBP + k] = sums[t] - v;
    if (t == 255) total[k] = sums[t];
}

// A3: bin packed (src<<SH|dlo) into fixed-stride bucket segments.
__global__ void k_bin(const int* __restrict__ src, const int* __restrict__ dst,
                      int E, const unsigned* __restrict__ blockOfs,
                      unsigned* __restrict__ epack) {
    __shared__ unsigned cur[NBP];
    int b = blockIdx.x, t = threadIdx.x;
    for (int i = t; i < NBP; i += BSE)
        cur[i] = (unsigned)i * FCAP + blockOfs[(size_t)b * NBP + i];
    __syncthreads();
    int lo = b * CH, hi = min(E, lo + CH);
    int i = lo + 4 * t;
    for (; i + 3 < hi; i += 4 * BSE) {
        int4 d4 = *(const int4*)(dst + i);
        int4 s4 = *(const int4*)(src + i);
        unsigned p0 = atomicAdd(&cur[((unsigned)d4.x) >> SH], 1u);
        unsigned p1 = atomicAdd(&cur[((unsigned)d4.y) >> SH], 1u);
        unsigned p2 = atomicAdd(&cur[((unsigned)d4.z) >> SH], 1u);
        unsigned p3 = atomicAdd(&cur[((unsigned)d4.w) >> SH], 1u);
        epack[p0] = ((unsigned)s4.x << SH) | (((unsigned)d4.x) & (NBW - 1u));
        epack[p1] = ((unsigned)s4.y << SH) | (((unsigned)d4.y) & (NBW - 1u));
        epack[p2] = ((unsigned)s4.z << SH) | (((unsigned)d4.z) & (NBW - 1u));
        epack[p3] = ((unsigned)s4.w << SH) | (((unsigned)d4.w) & (NBW - 1u));
    }
    for (i = lo + ((hi - lo) & ~3) + t; i < hi; i += BSE) {
        unsigned d = (unsigned)dst[i];
        unsigned pos = atomicAdd(&cur[d >> SH], 1u);
        epack[pos] = ((unsigned)src[i] << SH) | (d & (NBW - 1u));
    }
}

// B: per bucket — stage in LDS, count, scan, sort in LDS, coalesced writeback.
// Emits rowofs (absolute), rowcnt, x_scaled.
__global__ void k_build(unsigned* __restrict__ epack, const unsigned* __restrict__ total,
                        const float* __restrict__ x,
                        unsigned* __restrict__ rowofs, unsigned* __restrict__ rowcnt,
                        float* __restrict__ x_scaled, int N) {
    __shared__ unsigned stage[FCAP];
    __shared__ unsigned cnt[BSB];
    __shared__ unsigned sc[BSB];
    __shared__ unsigned cur[BSB];
    int k = blockIdx.x, t = threadIdx.x;           // 512 threads
    unsigned base = (unsigned)k * FCAP;
    int len = min((int)total[k], FCAP);
    for (int i = 4 * t; i + 3 < len; i += 4 * BSB)
        *(int4*)&stage[i] = *(const int4*)(epack + base + i);
    if (t < (len & 3)) stage[(len & ~3) + t] = epack[base + (len & ~3) + t];
    cnt[t] = 0;
    __syncthreads();
    for (int i = t; i < len; i += BSB) atomicAdd(&cnt[stage[i] & (NBW - 1u)], 1u);
    __syncthreads();
    unsigned c = cnt[t];
    sc[t] = c;
    __syncthreads();
    for (int off = 1; off < BSB; off <<= 1) {
        unsigned u = (t >= off) ? sc[t - off] : 0;
        __syncthreads();
        sc[t] += u;
        __syncthreads();
    }
    unsigned excl = sc[t] - c;
    cur[t] = excl;
    int node = k * NBW + t;
    if (node < N) {
        rowofs[node] = base + excl;
        rowcnt[node] = c;
        float di = rsqrtf((float)(c + 1));         // +1: self loop
        float4 xv = ((const float4*)x)[node];
        ((float4*)x_scaled)[node] = make_float4(xv.x * di, xv.y * di, xv.z * di, xv.w * di);
    }
    __syncthreads();
    unsigned r[RSTG];                               // lift to regs, then sort
    int nr = 0;
    for (int i = t; i < len; i += BSB) r[nr++] = stage[i];
    __syncthreads();
    for (int j = 0; j < nr; ++j) {
        unsigned p = r[j];
        unsigned pos = atomicAdd(&cur[p & (NBW - 1u)], 1u);
        stage[pos] = p >> SH;                       // stage = sorted src lists
    }
    __syncthreads();
    for (int i = 4 * t; i + 3 < len; i += 4 * BSB)  // coalesced writeback
        *(int4*)(epack + base + i) = *(const int4*)&stage[i];
    if (t < (len & 3)) epack[base + (len & ~3) + t] = stage[(len & ~3) + t];
}

// C1: pull-mode layer-1 aggregation + fused node math (no atomics).
__global__ void k_agg1(const unsigned* __restrict__ esorted, const unsigned* __restrict__ rowofs,
                       const unsigned* __restrict__ rowcnt,
                       const float* __restrict__ x_scaled,
                       const float* __restrict__ W1, const float* __restrict__ b1,
                       const float* __restrict__ W2,
                       float* __restrict__ z_scaled, int N) {
    int node = blockIdx.x * blockDim.x + threadIdx.x;
    if (node >= N) return;
    unsigned lo = rowofs[node], c = rowcnt[node], hi = lo + c;
    float di = rsqrtf((float)(c + 1));
    const float4* xs4 = (const float4*)x_scaled;
    float4 a0 = xs4[node];                          // self loop
    float4 a1 = make_float4(0.f, 0.f, 0.f, 0.f);
    float4 a2 = make_float4(0.f, 0.f, 0.f, 0.f);
    float4 a3 = make_float4(0.f, 0.f, 0.f, 0.f);
    unsigned i = lo;
    for (; i + 3 < hi; i += 4) {                    // 4 gathers in flight
        float4 v0 = xs4[esorted[i]],     v1 = xs4[esorted[i + 1]];
        float4 v2 = xs4[esorted[i + 2]], v3 = xs4[esorted[i + 3]];
        a0.x += v0.x; a0.y += v0.y; a0.z += v0.z; a0.w += v0.w;
        a1.x += v1.x; a1.y += v1.y; a1.z += v1.z; a1.w += v1.w;
        a2.x += v2.x; a2.y += v2.y; a2.z += v2.z; a2.w += v2.w;
        a3.x += v3.x; a3.y += v3.y; a3.z += v3.z; a3.w += v3.w;
    }
    for (; i < hi; ++i) {
        float4 v = xs4[esorted[i]];
        a0.x += v.x; a0.y += v.y; a0.z += v.z; a0.w += v.w;
    }
    float p0 = di * (a0.x + a1.x + a2.x + a3.x);
    float p1 = di * (a0.y + a1.y + a2.y + a3.y);
    float p2 = di * (a0.z + a1.z + a2.z + a3.z);
    float p3 = di * (a0.w + a1.w + a2.w + a3.w);
    float z = 0.0f;
    #pragma unroll
    for (int cc = 0; cc < 16; ++cc) {
        float h1 = p0 * W1[0 * 16 + cc] + p1 * W1[1 * 16 + cc]
                 + p2 * W1[2 * 16 + cc] + p3 * W1[3 * 16 + cc] + b1[cc];
        h1 = fmaxf(h1, 0.0f);
        z += h1 * W2[cc];
    }
    z_scaled[node] = z * di;
}

// C2: pull-mode layer-2 aggregation (no atomics).
__global__ void k_agg2(const unsigned* __restrict__ esorted, const unsigned* __restrict__ rowofs,
                       const unsigned* __restrict__ rowcnt,
                       const float* __restrict__ z_scaled,
                       const float* __restrict__ b2, float* __restrict__ out, int N) {
    int node = blockIdx.x * blockDim.x + threadIdx.x;
    if (node >= N) return;
    unsigned lo = rowofs[node], c = rowcnt[node], hi = lo + c;
    float di = rsqrtf((float)(c + 1));
    float a0 = z_scaled[node], a1 = 0.f, a2 = 0.f, a3 = 0.f;  // self loop in a0
    unsigned i = lo;
    for (; i + 3 < hi; i += 4) {
        a0 += z_scaled[esorted[i]];
        a1 += z_scaled[esorted[i + 1]];
        a2 += z_scaled[esorted[i + 2]];
        a3 += z_scaled[esorted[i + 3]];
    }
    for (; i < hi; ++i) a0 += z_scaled[esorted[i]];
    out[node] = di * (a0 + a1 + a2 + a3) + b2[0];
}

extern "C" void kernel_launch(void* const* d_in, const int* in_sizes, int n_in,
                              void* d_out, int out_size, void* d_ws, size_t ws_size,
                              hipStream_t stream) {
    const float* x  = (const float*)d_in[0];
    const int*   ei = (const int*)d_in[1];   // [2, E] as int32
    const float* W1 = (const float*)d_in[2];
    const float* b1 = (const float*)d_in[3];
    const float* W2 = (const float*)d_in[4];
    const float* b2 = (const float*)d_in[5];

    const int N = in_sizes[0] / 4;
    const int E = in_sizes[1] / 2;
    const int* src = ei;
    const int* dst = ei + E;
    const int nb = (N + NBW - 1) / NBW;      // 391
    const int NA = (E + CH - 1) / CH;        // 196 (must be <= 256 for scan)

    // Workspace (~20.5 MB): blockHist | blockOfs | total | epack[nb*FCAP] |
    //   rowofs[N] | rowcnt[N] | x_scaled[N*4] | z_scaled[N]
    char* ws = (char*)d_ws;
    unsigned* blockHist = (unsigned*)ws;  ws += (size_t)NA * NBP * 4;
    unsigned* blockOfs  = (unsigned*)ws;  ws += (size_t)NA * NBP * 4;
    unsigned* total     = (unsigned*)ws;  ws += (size_t)NBP * 4;
    unsigned* epack     = (unsigned*)ws;  ws += (size_t)nb * FCAP * 4;
    unsigned* rowofs    = (unsigned*)ws;  ws += (size_t)N * 4;
    unsigned* rowcnt    = (unsigned*)ws;  ws += (size_t)N * 4;
    float*    x_scaled  = (float*)ws;     ws += (size_t)N * 4 * 4;
    float*    z_scaled  = (float*)ws;     ws += (size_t)N * 4;
    float* out = (float*)d_out;

    k_hist     <<<NA, BSE, 0, stream>>>(dst, E, blockHist);
    k_scan_col <<<nb, 256, 0, stream>>>(blockHist, blockOfs, total, NA);
    k_bin      <<<NA, BSE, 0, stream>>>(src, dst, E, blockOfs, epack);
    k_build    <<<nb, BSB, 0, stream>>>(epack, total, x, rowofs, rowcnt, x_scaled, N);
    k_agg1     <<<(N + 255) / 256, 256, 0, stream>>>(epack, rowofs, rowcnt, x_scaled,
                                                     W1, b1, W2, z_scaled, N);
    k_agg2     <<<(N + 255) / 256, 256, 0, stream>>>(epack, rowofs, rowcnt, z_scaled,
                                                     b2, out, N);
}